// Round 13
// baseline (291.339 us; speedup 1.0000x reference)
//
#include <hip/hip_runtime.h>
#include <hip/hip_bf16.h>

#define C 256
#define HID 128
#define Bb_ 2
#define Hh 64
#define Ww 64
#define Nn_ 4096
#define NP 16
#define NC 16
#define KVSPLIT 8
#define KVB 32

typedef __bf16 bf16x8 __attribute__((ext_vector_type(8)));
typedef float f32x4 __attribute__((ext_vector_type(4)));
typedef float f32x16 __attribute__((ext_vector_type(16)));

// ---------------------------------------------------------------------------
// Coalesced tiled LayerNorm -> x1T, x2T bf16 [B][N][C]; also emits qryT bf16.
__global__ __launch_bounds__(256) void lnT_kernel(
    const float* __restrict__ x,
    const float* __restrict__ g1, const float* __restrict__ b1,
    const float* __restrict__ g2, const float* __restrict__ b2,
    __hip_bfloat16* __restrict__ x1T, __hip_bfloat16* __restrict__ x2T,
    __hip_bfloat16* __restrict__ qryTb)
{
    int blk = blockIdx.x;
    int b = blk >> 6;
    int n0 = (blk & 63) << 6;
    int t = threadIdx.x;
    __shared__ __hip_bfloat16 xs[64][258];
    __shared__ float rs4[4][64], rq4[4][64], mean[64], inv[64];
    int j = t & 63, cg = t >> 6;
    float s = 0.f, q = 0.f;
    for (int it = 0; it < 64; ++it) {
        int c = it * 4 + cg;
        float v = x[((long)b * C + c) * Nn_ + n0 + j];
        xs[j][c] = __float2bfloat16(v);
        s += v; q += v * v;
    }
    rs4[cg][j] = s; rq4[cg][j] = q;
    __syncthreads();
    if (t < 64) {
        float S = rs4[0][t] + rs4[1][t] + rs4[2][t] + rs4[3][t];
        float Q = rq4[0][t] + rq4[1][t] + rq4[2][t] + rq4[3][t];
        float m = S * (1.0f / C);
        float var = Q * (1.0f / C) - m * m;
        mean[t] = m; inv[t] = rsqrtf(var + 1e-5f);
    }
    __syncthreads();
    float G1 = g1[t], B1 = b1[t], G2 = g2[t], B2 = b2[t];
    for (int j2 = 0; j2 < 64; ++j2) {
        float v = __bfloat162float(xs[j2][t]);
        float xn = (v - mean[j2]) * inv[j2];
        long o = ((long)b * Nn_ + n0 + j2) * C + t;
        x1T[o] = __float2bfloat16(xn * G1 + B1);
        x2T[o] = __float2bfloat16(xn * G2 + B2);
        qryTb[o] = xs[j2][t];
    }
}

// ---------------------------------------------------------------------------
__global__ __launch_bounds__(256) void gate_kernel(
    const float* __restrict__ arch, const float* __restrict__ Wg,
    const float* __restrict__ bg, float* __restrict__ gate)
{
    int b = blockIdx.x;
    int o = threadIdx.x;
    __shared__ float guide[C];
    float s = 0.f;
    for (int p = 0; p < NP; ++p) s += arch[(long)b * NP * C + (long)p * C + o];
    guide[o] = s * (1.0f / NP);
    __syncthreads();
    float acc = bg[o];
    for (int cc = 0; cc < C; ++cc) acc += guide[cc] * Wg[(long)o * C + cc];
    gate[b * C + o] = 1.0f / (1.0f + __expf(-acc));
}

// ---------------------------------------------------------------------------
#define QSCALE 0.09016844005429271f   // log2(e)/16
__global__ __launch_bounds__(256) void build_wqkv(
    const float* __restrict__ Wqkv, const float* __restrict__ bqkv,
    const float* __restrict__ gate,
    __hip_bfloat16* __restrict__ WqkvG, float* __restrict__ biasCol)
{
    long i = (long)blockIdx.x * 256 + threadIdx.x;
    long total = (long)Bb_ * 3 * C * C;
    if (i < total) {
        long b = i / (3 * C * C);
        long rem = i % (3 * C * C);
        int o = (int)(rem / C);
        float v = Wqkv[rem];
        if (o < C) v *= QSCALE;
        else if (o < 2 * C) v *= gate[b * C + (o - C)];
        WqkvG[i] = __float2bfloat16(v);
    }
    if (i < (long)Bb_ * 3 * C) {
        long b = i / (3 * C);
        int o = (int)(i % (3 * C));
        float v = bqkv[o];
        if (o < C) v *= QSCALE;
        else if (o < 2 * C) v *= gate[b * C + (o - C)];
        biasCol[i] = v;
    }
}

// ---------------------------------------------------------------------------
__global__ __launch_bounds__(256) void cast_all(
    const float* __restrict__ Wproj, const float* __restrict__ Wf2,
    const float* __restrict__ Wf1,
    __hip_bfloat16* __restrict__ Wprojb, __hip_bfloat16* __restrict__ Wf2b,
    __hip_bfloat16* __restrict__ Wtap)
{
    long i = (long)blockIdx.x * 256 + threadIdx.x;
    const long nP = (long)C * C;
    const long nT = 9l * C * 2 * C;
    if (i < nP) { Wprojb[i] = __float2bfloat16(Wproj[i]); return; }
    i -= nP;
    if (i < nP) { Wf2b[i] = __float2bfloat16(Wf2[i]); return; }
    i -= nP;
    if (i < nT) {
        int tap = (int)(i / (C * 2 * C));
        long rem = i % (C * 2 * C);
        int o = (int)(rem / (2 * C)), ic = (int)(rem % (2 * C));
        Wtap[i] = __float2bfloat16(Wf1[((long)o * 2 * C + ic) * 9 + tap]);
    }
}

// ---------------------------------------------------------------------------
__global__ __launch_bounds__(256) void cross_prep(
    const float* __restrict__ ctx, const float* __restrict__ Wkv,
    const float* __restrict__ bkv, const float* __restrict__ Wq,
    const float* __restrict__ bq, const float* __restrict__ Wout,
    float* __restrict__ ktil, float* __restrict__ beta,
    float* __restrict__ vtil)
{
    int b = blockIdx.x >> 4, m = blockIdx.x & 15;
    int t = threadIdx.x;
    __shared__ float cs[C], kl[C], red[128];
    cs[t] = ctx[((long)b * NC + m) * C + t];
    __syncthreads();
    float acc = bkv[t];
    for (int c = 0; c < C; ++c) acc += cs[c] * Wkv[(long)t * C + c];
    kl[t] = acc;
    __syncthreads();
    const float scc = 0.08838834764831845f;
    float kt = 0.f;
    for (int h = 0; h < HID; ++h) kt += kl[h] * Wq[(long)h * C + t];
    ktil[((long)b * NC + m) * C + t] = kt * scc;
    float vt = 0.f;
    for (int h = 0; h < HID; ++h) vt += kl[HID + h] * Wout[(long)t * HID + h];
    vtil[((long)b * C + t) * NC + m] = vt;
    if (t < 128) red[t] = bq[t] * kl[t];
    __syncthreads();
    for (int s = 64; s > 0; s >>= 1) {
        if (t < s) red[t] += red[t + s];
        __syncthreads();
    }
    if (t == 0) beta[b * NC + m] = red[0] * scc;
}

// ---------------------------------------------------------------------------
__global__ __launch_bounds__(256) void cross_fused(
    const __hip_bfloat16* __restrict__ x2T, const __hip_bfloat16* __restrict__ qryTb,
    const float* __restrict__ ktil, const float* __restrict__ beta,
    const float* __restrict__ vtil, const float* __restrict__ bout,
    __hip_bfloat16* __restrict__ catT)
{
    int blk = blockIdx.x;
    int b = blk >> 6;
    long n = (long)(blk & 63) * 64 + (threadIdx.x >> 2);
    int cg = threadIdx.x & 3;
    int t = threadIdx.x;
    __shared__ float kt[NC * C];
    __shared__ float vt[C * NC];
    for (int r = 0; r < 16; ++r) {
        int idx = r * 256 + t;
        int m = idx >> 8, c = idx & 255;
        kt[m * 256 + (c & 63) * 4 + (c >> 6)] = ktil[((long)b * NC + m) * C + c];
        int c2 = idx >> 4, m2 = idx & 15;
        vt[((c2 & 63) * 4 + (c2 >> 6)) * 16 + m2] = vtil[((long)b * C + c2) * NC + m2];
    }
    __syncthreads();

    float s[NC];
    #pragma unroll
    for (int m = 0; m < NC; ++m) s[m] = 0.f;
    const __hip_bfloat16* xr = x2T + ((long)b * Nn_ + n) * C + cg * 64;
    for (int c8 = 0; c8 < 8; ++c8) {
        bf16x8 xv = *(const bf16x8*)(xr + c8 * 8);
        #pragma unroll
        for (int e = 0; e < 8; ++e) {
            float xf = (float)xv[e];
            int ic = c8 * 8 + e;
            #pragma unroll
            for (int m = 0; m < NC; ++m)
                s[m] += xf * kt[m * 256 + ic * 4 + cg];
        }
    }
    #pragma unroll
    for (int m = 0; m < NC; ++m) {
        s[m] += __shfl_xor(s[m], 1);
        s[m] += __shfl_xor(s[m], 2);
        s[m] += beta[b * NC + m];
    }
    float mx = -1e30f;
    #pragma unroll
    for (int m = 0; m < NC; ++m) mx = fmaxf(mx, s[m]);
    float sum = 0.f;
    #pragma unroll
    for (int m = 0; m < NC; ++m) { s[m] = __expf(s[m] - mx); sum += s[m]; }
    float dn = 1.0f / sum;

    const __hip_bfloat16* qr = qryTb + ((long)b * Nn_ + n) * C + cg * 64;
    __hip_bfloat16* outp = catT + ((long)b * Nn_ + n) * (2 * C) + C + cg * 64;
    for (int c8 = 0; c8 < 8; ++c8) {
        union { ushort4 u; __hip_bfloat16 h[4]; } cv0, cv1;
        #pragma unroll
        for (int e = 0; e < 8; ++e) {
            int ic = c8 * 8 + e;
            int c = cg * 64 + ic;
            float acc = __bfloat162float(qr[ic]) + bout[c];
            float pv = 0.f;
            #pragma unroll
            for (int m = 0; m < NC; ++m)
                pv += vt[(ic * 4 + cg) * 16 + m] * s[m];
            acc += pv * dn;
            if (e < 4) cv0.h[e] = __float2bfloat16(acc);
            else       cv1.h[e - 4] = __float2bfloat16(acc);
        }
        *(ushort4*)(outp + c8 * 8) = cv0.u;
        *(ushort4*)(outp + c8 * 8 + 4) = cv1.u;
    }
}

// ---------------------------------------------------------------------------
// MFMA bf16 GEMM; resid may be fp32 or bf16.
__global__ __launch_bounds__(256) void gemm_bt(
    const __hip_bfloat16* __restrict__ A,
    const __hip_bfloat16* __restrict__ Bt,
    float* __restrict__ D,
    __hip_bfloat16* __restrict__ Dbf,
    int M, int N, int K, int lda, int ldb, int ldd,
    long batchA, long batchB, long batchD,
    const float* __restrict__ biasRow,
    const float* __restrict__ biasCol, long bcStride,
    const float* __restrict__ resid,
    const __hip_bfloat16* __restrict__ residB, int ldr, long batchR,
    float alpha, int relu)
{
    __shared__ __align__(16) __hip_bfloat16 As[128 * 32];
    __shared__ __align__(16) __hip_bfloat16 Bs[128 * 32];
    int bz = blockIdx.z;
    const __hip_bfloat16* Ab = A + (long)bz * batchA;
    const __hip_bfloat16* Bb = Bt + (long)bz * batchB;
    int m0 = blockIdx.y * 128, n0 = blockIdx.x * 128;
    int tid = threadIdx.x;
    int lane = tid & 63, wave = tid >> 6;
    int wr = wave >> 1, wc = wave & 1;
    int lr = lane & 15, lg = lane >> 4;

    f32x4 acc[4][4];
    #pragma unroll
    for (int i = 0; i < 4; ++i)
        #pragma unroll
        for (int j = 0; j < 4; ++j)
            #pragma unroll
            for (int r = 0; r < 4; ++r) acc[i][j][r] = 0.f;

    for (int k0 = 0; k0 < K; k0 += 32) {
        #pragma unroll
        for (int q = 0; q < 2; ++q) {
            int idx = q * 256 + tid;
            int row = idx >> 2;
            int ke = (idx & 3) * 8;
            uint4 va = *(const uint4*)(Ab + (long)(m0 + row) * lda + k0 + ke);
            uint4 vb = *(const uint4*)(Bb + (long)(n0 + row) * ldb + k0 + ke);
            ((uint4*)As)[idx] = va;
            ((uint4*)Bs)[idx] = vb;
        }
        __syncthreads();
        bf16x8 af[4], bfr[4];
        #pragma unroll
        for (int i = 0; i < 4; ++i)
            af[i] = *(const bf16x8*)(As + (wr * 64 + i * 16 + lr) * 32 + lg * 8);
        #pragma unroll
        for (int j = 0; j < 4; ++j)
            bfr[j] = *(const bf16x8*)(Bs + (wc * 64 + j * 16 + lr) * 32 + lg * 8);
        #pragma unroll
        for (int i = 0; i < 4; ++i)
            #pragma unroll
            for (int j = 0; j < 4; ++j)
                acc[i][j] = __builtin_amdgcn_mfma_f32_16x16x32_bf16(af[i], bfr[j], acc[i][j], 0, 0, 0);
        __syncthreads();
    }

    int colc = n0 + wc * 64 + lr;
    #pragma unroll
    for (int i = 0; i < 4; ++i) {
        #pragma unroll
        for (int r = 0; r < 4; ++r) {
            int row = m0 + wr * 64 + i * 16 + lg * 4 + r;
            float brv = biasRow ? biasRow[row] : 0.f;
            #pragma unroll
            for (int j = 0; j < 4; ++j) {
                int cc = colc + j * 16;
                float v = acc[i][j][r] * alpha + brv;
                if (biasCol) v += biasCol[bz * bcStride + cc];
                if (resid) v += resid[(long)bz * batchR + (long)row * ldr + cc];
                if (residB) v += __bfloat162float(residB[(long)bz * batchR + (long)row * ldr + cc]);
                if (relu) v = fmaxf(v, 0.f);
                long oa = (long)bz * batchD + (long)row * ldd + cc;
                if (Dbf) Dbf[oa] = __float2bfloat16(v);
                else     D[oa] = v;
            }
        }
    }
}

// ---------------------------------------------------------------------------
__global__ __launch_bounds__(256) void extract_v(
    const __hip_bfloat16* __restrict__ qkvT, __hip_bfloat16* __restrict__ vB)
{
    int b = blockIdx.z;
    int c0 = blockIdx.y * 64, m0 = blockIdx.x * 64;
    __shared__ __hip_bfloat16 tb[64][66];
    int tx = threadIdx.x & 63, tg = threadIdx.x >> 6;
    for (int rr = tg; rr < 64; rr += 4)
        tb[rr][tx] = qkvT[((long)b * Nn_ + m0 + rr) * (3 * C) + 2 * C + c0 + tx];
    __syncthreads();
    for (int rr = tg; rr < 64; rr += 4)
        vB[((long)b * C + c0 + rr) * Nn_ + m0 + tx] = tb[tx][rr];
}

// ---------------------------------------------------------------------------
// Flash attention v5: 32x32x16 MFMA, fragment-linear K/V LDS (conflict-free,
// immediate offsets), producer/consumer wave split (dg0 computes QK+P once),
// no-max log2-domain softmax. grid (64 Qtiles, KVSPLIT=8, B), 256 threads:
// wave w: qg = w>>1 (32 q-rows), dg = w&1 (128-d half).
__global__ __launch_bounds__(256) void flash_attn(
    const __hip_bfloat16* __restrict__ qkvT,
    const __hip_bfloat16* __restrict__ vB,
    __hip_bfloat16* __restrict__ Opart,   // [B][KVSPLIT][N][256] bf16 unnormalized
    float* __restrict__ lsum)             // [B][KVSPLIT][N]
{
    int qb = blockIdx.x, sp = blockIdx.y, b = blockIdx.z;
    int n0 = qb * 64;
    int tid = threadIdx.x;
    int lane = tid & 63, w = tid >> 6;
    int l31 = lane & 31, l5 = lane >> 5;
    int qg = w >> 1, dg = w & 1;

    __shared__ __align__(16) char Ks[16 * 1024];   // frag cs: K[kv=l31][cs*16+l5*8+j]
    __shared__ __align__(16) char Vs[16 * 1024];   // frag f:  V[(f>>1)*32+l31][(f&1)*16+l5*8+j]
    __shared__ __align__(16) char Pw[2 * 2048];    // per qg: packed 16x128B, XOR swz

    // Q fragments (only dg0 uses them; uniform allocation)
    bf16x8 qf[16];
    {
        const __hip_bfloat16* qp = qkvT + ((long)b * Nn_ + n0 + qg * 32 + l31) * (3 * C) + l5 * 8;
        #pragma unroll
        for (int cs = 0; cs < 16; ++cs)
            qf[cs] = *(const bf16x8*)(qp + cs * 16);
    }

    const __hip_bfloat16* kbase = qkvT + ((long)b * Nn_) * (3 * C) + C;
    const __hip_bfloat16* vbase = vB + (long)b * C * Nn_;
    int kvBeg = sp * (Nn_ / KVSPLIT);

    // staging: thread stages frag (ps*4+w), lane-chunk `lane` for both K and V
    // K source col = (ps*4+w)*16 + l5*8, row = kv0 + l31
    // V source: d = ps*64 + (w>>1)*32 + l31, col = kv0 + (w&1)*16 + l5*8
    int kcol = w * 16 + l5 * 8;                    // + ps*64 via imm offset
    long vrowbase = (long)((w >> 1) * 32 + l31) * Nn_ + (w & 1) * 16 + l5 * 8;
    char* kdst = Ks + w * 1024 + lane * 16;        // + ps*4096 imm
    char* vdst = Vs + w * 1024 + lane * 16;        // + ps*4096 imm

    // P read/write invariants
    int pq = l31;                                   // consumer q-row
    int prd0 = (pq >> 1) * 128 + ((((pq & 1) * 64) + 0 * 32 + l5 * 16) ^ (((pq >> 1) & 7) << 4));
    int prd1 = (pq >> 1) * 128 + ((((pq & 1) * 64) + 1 * 32 + l5 * 16) ^ (((pq >> 1) & 7) << 4));
    char* pslab = Pw + qg * 2048;

    f32x16 Oacc[4];
    #pragma unroll
    for (int jd = 0; jd < 4; ++jd)
        #pragma unroll
        for (int r = 0; r < 16; ++r) Oacc[jd][r] = 0.f;
    float l_r[16];
    #pragma unroll
    for (int r = 0; r < 16; ++r) l_r[r] = 0.f;

    const int NT = (Nn_ / KVSPLIT) / KVB;   // 16
    for (int t = 0; t < NT; ++t) {
        int kv0 = kvBeg + t * KVB;
        // ---- stage K + V (frag-linear; regs die at LDS write)
        {
            const __hip_bfloat16* kp = kbase + (long)(kv0 + l31) * (3 * C) + kcol;
            uint4 k0v = *(const uint4*)(kp);
            uint4 k1v = *(const uint4*)(kp + 64);
            uint4 k2v = *(const uint4*)(kp + 128);
            uint4 k3v = *(const uint4*)(kp + 192);
            *(uint4*)(kdst)          = k0v;
            *(uint4*)(kdst + 4096)   = k1v;
            *(uint4*)(kdst + 8192)   = k2v;
            *(uint4*)(kdst + 12288)  = k3v;
            const __hip_bfloat16* vp = vbase + vrowbase + kv0;
            uint4 v0v = *(const uint4*)(vp);
            uint4 v1v = *(const uint4*)(vp + 64l * Nn_);
            uint4 v2v = *(const uint4*)(vp + 128l * Nn_);
            uint4 v3v = *(const uint4*)(vp + 192l * Nn_);
            *(uint4*)(vdst)          = v0v;
            *(uint4*)(vdst + 4096)   = v1v;
            *(uint4*)(vdst + 8192)   = v2v;
            *(uint4*)(vdst + 12288)  = v3v;
        }
        __syncthreads();
        // ---- QK^T + exp2 + P (producer waves only)
        if (dg == 0) {
            f32x16 sacc;
            #pragma unroll
            for (int r = 0; r < 16; ++r) sacc[r] = 0.f;
            const char* krd = Ks + lane * 16;
            __builtin_amdgcn_s_setprio(1);
            #pragma unroll
            for (int cs = 0; cs < 16; ++cs) {
                bf16x8 kf = *(const bf16x8*)(krd + cs * 1024);
                sacc = __builtin_amdgcn_mfma_f32_32x32x16_bf16(qf[cs], kf, sacc, 0, 0, 0);
            }
            __builtin_amdgcn_s_setprio(0);
            #pragma unroll
            for (int reg = 0; reg < 16; ++reg) {
                float p = __builtin_amdgcn_exp2f(sacc[reg]);
                l_r[reg] += p;
                int q = (reg & 3) + 8 * (reg >> 2) + 4 * l5;
                int kv = l31;
                int byte = (q >> 1) * 128 +
                           (((((q & 1) * 64) + (kv >> 3) * 16) ^ (((q >> 1) & 7) << 4)) + (kv & 7) * 2);
                *(__hip_bfloat16*)(pslab + byte) = __float2bfloat16(p);
            }
        }
        __syncthreads();
        // ---- PV (all waves; V frags for this wave's d-half)
        {
            bf16x8 pf0 = *(const bf16x8*)(pslab + prd0);
            bf16x8 pf1 = *(const bf16x8*)(pslab + prd1);
            const char* vrd = Vs + dg * 8192 + lane * 16;
            __builtin_amdgcn_s_setprio(1);
            #pragma unroll
            for (int jd = 0; jd < 4; ++jd) {
                bf16x8 vf0 = *(const bf16x8*)(vrd + jd * 2048);
                Oacc[jd] = __builtin_amdgcn_mfma_f32_32x32x16_bf16(pf0, vf0, Oacc[jd], 0, 0, 0);
                bf16x8 vf1 = *(const bf16x8*)(vrd + jd * 2048 + 1024);
                Oacc[jd] = __builtin_amdgcn_mfma_f32_32x32x16_bf16(pf1, vf1, Oacc[jd], 0, 0, 0);
            }
            __builtin_amdgcn_s_setprio(0);
        }
        __syncthreads();
    }

    // row-sums: reduce over 32 kv-cols (within each 32-lane half)
    if (dg == 0) {
        #pragma unroll
        for (int reg = 0; reg < 16; ++reg) {
            float v = l_r[reg];
            #pragma unroll
            for (int off = 1; off <= 16; off <<= 1)
                v += __shfl_xor(v, off);
            l_r[reg] = v;
        }
        if (l31 == 0) {
            float* lp = lsum + ((long)b * KVSPLIT + sp) * Nn_ + n0 + qg * 32;
            #pragma unroll
            for (int reg = 0; reg < 16; ++reg) {
                int q = (reg & 3) + 8 * (reg >> 2) + 4 * l5;
                lp[q] = l_r[reg];
            }
        }
    }

    __hip_bfloat16* Op = Opart + (((long)b * KVSPLIT + sp) * Nn_ + n0 + qg * 32) * 256
                       + dg * 128 + l31;
    #pragma unroll
    for (int jd = 0; jd < 4; ++jd)
        #pragma unroll
        for (int reg = 0; reg < 16; ++reg) {
            int q = (reg & 3) + 8 * (reg >> 2) + 4 * l5;
            Op[(long)q * 256 + jd * 32] = __float2bfloat16(Oacc[jd][reg]);
        }
}

// ---------------------------------------------------------------------------
__global__ __launch_bounds__(256) void merge_flash(
    const __hip_bfloat16* __restrict__ Opart, const float* __restrict__ lsum,
    __hip_bfloat16* __restrict__ refsT)
{
    long gi = (long)blockIdx.x * 256 + threadIdx.x;
    long row = gi >> 6;
    int c4 = (int)(gi & 63) * 4;
    long b = row / Nn_, n = row % Nn_;
    float l = 0.f;
    float o0 = 0.f, o1 = 0.f, o2 = 0.f, o3 = 0.f;
    #pragma unroll
    for (int sp = 0; sp < KVSPLIT; ++sp) {
        long rr = (b * KVSPLIT + sp) * Nn_ + n;
        l += lsum[rr];
        union { ushort4 u; __hip_bfloat16 h[4]; } rv;
        rv.u = *(const ushort4*)(Opart + rr * 256 + c4);
        o0 += __bfloat162float(rv.h[0]);
        o1 += __bfloat162float(rv.h[1]);
        o2 += __bfloat162float(rv.h[2]);
        o3 += __bfloat162float(rv.h[3]);
    }
    float dn = 1.0f / l;
    union { ushort4 u; __hip_bfloat16 h[4]; } cv;
    cv.h[0] = __float2bfloat16(o0 * dn);
    cv.h[1] = __float2bfloat16(o1 * dn);
    cv.h[2] = __float2bfloat16(o2 * dn);
    cv.h[3] = __float2bfloat16(o3 * dn);
    *(ushort4*)(refsT + (b * Nn_ + n) * 256 + c4) = cv.u;
}

// ---------------------------------------------------------------------------
__global__ __launch_bounds__(256) void conv3x3_gemm(
    const __hip_bfloat16* __restrict__ catT,
    const __hip_bfloat16* __restrict__ Wtap,
    __hip_bfloat16* __restrict__ partials)
{
    __shared__ __align__(16) __hip_bfloat16 As[128 * 32];
    __shared__ __align__(16) __hip_bfloat16 Bs[128 * 32];
    int z = blockIdx.z;
    int b = z / 3, sp = z % 3;
    int dh = sp - 1;
    int o0 = blockIdx.x * 128, m0 = blockIdx.y * 128;
    int tid = threadIdx.x;
    int lane = tid & 63, wave = tid >> 6;
    int wr = wave >> 1, wc = wave & 1;
    int lr = lane & 15, lg = lane >> 4;
    const __hip_bfloat16* cb = catT + (long)b * Nn_ * (2 * C);

    f32x4 acc[4][4];
    #pragma unroll
    for (int i = 0; i < 4; ++i)
        #pragma unroll
        for (int j = 0; j < 4; ++j)
            #pragma unroll
            for (int r = 0; r < 4; ++r) acc[i][j][r] = 0.f;

    for (int kw = 0; kw < 3; ++kw) {
        int dw = kw - 1;
        const __hip_bfloat16* wt = Wtap + (long)(sp * 3 + kw) * C * (2 * C);
        for (int k0 = 0; k0 < 2 * C; k0 += 32) {
            #pragma unroll
            for (int q = 0; q < 2; ++q) {
                int idx = q * 256 + tid;
                int row = idx >> 2;
                int ke = (idx & 3) * 8;
                int gm = m0 + row;
                int h = (gm >> 6) + dh, w2 = (gm & 63) + dw;
                uint4 va = {0, 0, 0, 0};
                if ((unsigned)h < 64u && (unsigned)w2 < 64u)
                    va = *(const uint4*)(cb + ((long)((h << 6) + w2)) * (2 * C) + k0 + ke);
                ((uint4*)As)[idx] = va;
                ((uint4*)Bs)[idx] = *(const uint4*)(wt + (long)(o0 + row) * (2 * C) + k0 + ke);
            }
            __syncthreads();
            bf16x8 af[4], bfr[4];
            #pragma unroll
            for (int i = 0; i < 4; ++i)
                af[i] = *(const bf16x8*)(As + (wr * 64 + i * 16 + lr) * 32 + lg * 8);
            #pragma unroll
            for (int j = 0; j < 4; ++j)
                bfr[j] = *(const bf16x8*)(Bs + (wc * 64 + j * 16 + lr) * 32 + lg * 8);
            #pragma unroll
            for (int i = 0; i < 4; ++i)
                #pragma unroll
                for (int j = 0; j < 4; ++j)
                    acc[i][j] = __builtin_amdgcn_mfma_f32_16x16x32_bf16(af[i], bfr[j], acc[i][j], 0, 0, 0);
            __syncthreads();
        }
    }

    __hip_bfloat16* Dp = partials + ((long)(b * 3 + sp) * Nn_ + m0) * 256;
    #pragma unroll
    for (int i = 0; i < 4; ++i)
        #pragma unroll
        for (int r = 0; r < 4; ++r) {
            int row = wr * 64 + i * 16 + lg * 4 + r;
            #pragma unroll
            for (int j = 0; j < 4; ++j)
                Dp[(long)row * 256 + o0 + wc * 64 + j * 16 + lr] =
                    __float2bfloat16(acc[i][j][r]);
        }
}

// ---------------------------------------------------------------------------
__global__ __launch_bounds__(256) void reduce_partials(
    const __hip_bfloat16* __restrict__ part, long partStride,
    __hip_bfloat16* __restrict__ out, long n)
{
    long i = ((long)blockIdx.x * 256 + threadIdx.x) * 4;
    if (i >= n) return;
    float a[4] = {0.f, 0.f, 0.f, 0.f};
    #pragma unroll
    for (int sp = 0; sp < 3; ++sp) {
        union { ushort4 u; __hip_bfloat16 h[4]; } rv;
        rv.u = *(const ushort4*)(part + (long)sp * partStride + i);
        #pragma unroll
        for (int k = 0; k < 4; ++k) a[k] += __bfloat162float(rv.h[k]);
    }
    union { ushort4 u; __hip_bfloat16 h[4]; } cv;
    #pragma unroll
    for (int k = 0; k < 4; ++k)
        cv.h[k] = __float2bfloat16(fmaxf(a[k], 0.f));
    *(ushort4*)(out + i) = cv.u;
}

// ---------------------------------------------------------------------------
extern "C" void kernel_launch(void* const* d_in, const int* in_sizes, int n_in,
                              void* d_out, int out_size, void* d_ws, size_t ws_size,
                              hipStream_t stream)
{
    const float* qry   = (const float*)d_in[0];
    const float* arch  = (const float*)d_in[1];
    const float* ctx   = (const float*)d_in[2];
    const float* ln1_g = (const float*)d_in[3];
    const float* ln1_b = (const float*)d_in[4];
    const float* Wqkv  = (const float*)d_in[5];
    const float* bqkv  = (const float*)d_in[6];
    const float* Wproj = (const float*)d_in[7];
    const float* bproj = (const float*)d_in[8];
    const float* Wg    = (const float*)d_in[9];
    const float* bg    = (const float*)d_in[10];
    const float* ln2_g = (const float*)d_in[11];
    const float* ln2_b = (const float*)d_in[12];
    const float* Wq    = (const float*)d_in[13];
    const float* bq    = (const float*)d_in[14];
    const float* Wkv   = (const float*)d_in[15];
    const float* bkv   = (const float*)d_in[16];
    const float* Wout  = (const float*)d_in[17];
    const float* bout  = (const float*)d_in[18];
    const float* Wf1   = (const float*)d_in[19];
    const float* Wf2   = (const float*)d_in[20];
    const float* bf2   = (const float*)d_in[21];
    float* out = (float*)d_out;

    const long CN = (long)C * Nn_;
    const long MN = (long)Nn_ * C;
    char* ws = (char*)d_ws;
    size_t off = 0;
    auto alloc = [&](size_t bytes) -> char* {
        char* p = ws + off;
        off += (bytes + 255) & ~size_t(255);
        return p;
    };
    float* lbuf     = (float*)alloc((long)Bb_ * KVSPLIT * Nn_ * 4);
    float* gate     = (float*)alloc(Bb_ * C * 4);
    float* biasCol  = (float*)alloc((long)Bb_ * 3 * C * 4);
    float* ktil     = (float*)alloc((long)Bb_ * NC * C * 4);
    float* betab    = (float*)alloc((long)Bb_ * NC * 4);
    float* vtil     = (float*)alloc((long)Bb_ * C * NC * 4);
    __hip_bfloat16* Opart = (__hip_bfloat16*)alloc((long)Bb_ * KVSPLIT * MN * 2);
    __hip_bfloat16* convPart = (__hip_bfloat16*)alloc((long)Bb_ * 3 * MN * 2);
    __hip_bfloat16* qryTb = (__hip_bfloat16*)alloc(Bb_ * MN * 2);
    __hip_bfloat16* x1T   = (__hip_bfloat16*)alloc(Bb_ * MN * 2);
    __hip_bfloat16* x2T   = (__hip_bfloat16*)alloc(Bb_ * MN * 2);
    __hip_bfloat16* qkvT  = (__hip_bfloat16*)alloc((long)Bb_ * Nn_ * 3 * C * 2);
    __hip_bfloat16* vB    = (__hip_bfloat16*)alloc(Bb_ * CN * 2);
    __hip_bfloat16* refsT = (__hip_bfloat16*)alloc(Bb_ * MN * 2);
    __hip_bfloat16* catT  = (__hip_bfloat16*)alloc((long)Bb_ * Nn_ * 2 * C * 2);
    __hip_bfloat16* y1T   = (__hip_bfloat16*)alloc(Bb_ * MN * 2);
    __hip_bfloat16* WqkvG = (__hip_bfloat16*)alloc((long)Bb_ * 3 * C * C * 2);
    __hip_bfloat16* Wprojb= (__hip_bfloat16*)alloc((long)C * C * 2);
    __hip_bfloat16* Wf2b  = (__hip_bfloat16*)alloc((long)C * C * 2);
    __hip_bfloat16* Wtap  = (__hip_bfloat16*)alloc((long)9 * C * 2 * C * 2);

    // 1. layernorm (+ bf16 qry transpose fused)
    lnT_kernel<<<Bb_ * (Nn_ / 64), 256, 0, stream>>>(
        qry, ln1_g, ln1_b, ln2_g, ln2_b, x1T, x2T, qryTb);

    // 2. gate + weight prep + cross prep
    gate_kernel<<<Bb_, 256, 0, stream>>>(arch, Wg, bg, gate);
    build_wqkv<<<(Bb_ * 3 * C * C + 255) / 256, 256, 0, stream>>>(Wqkv, bqkv, gate, WqkvG, biasCol);
    {
        long total = (long)C * C * 2 + 9l * C * 2 * C;
        cast_all<<<(int)((total + 255) / 256), 256, 0, stream>>>(
            Wproj, Wf2, Wf1, Wprojb, Wf2b, Wtap);
    }
    cross_prep<<<Bb_ * NC, 256, 0, stream>>>(ctx, Wkv, bkv, Wq, bq, Wout, ktil, betab, vtil);

    // 3. qkvT = x1T @ WqkvG^T + biasCol  -> bf16 [B][N][768]
    gemm_bt<<<dim3(6, 32, Bb_), 256, 0, stream>>>(
        x1T, WqkvG, nullptr, qkvT, Nn_, 3 * C, C, C, C, 3 * C,
        MN, (long)3 * C * C, (long)Nn_ * 3 * C,
        nullptr, biasCol, 3 * C, nullptr, nullptr, 0, 0, 1.0f, 0);

    // 4. v -> vB [B][C][N]
    extract_v<<<dim3(Nn_ / 64, C / 64, Bb_), 256, 0, stream>>>(qkvT, vB);

    // 5. flash attention + merge -> refsT bf16 [B][N][C]
    flash_attn<<<dim3(Nn_ / 64, KVSPLIT, Bb_), 256, 0, stream>>>(qkvT, vB, Opart, lbuf);
    merge_flash<<<(int)((long)Bb_ * Nn_ * 64 / 256), 256, 0, stream>>>(Opart, lbuf, refsT);

    // 6. catT[:, :256] = qryTb + refsT @ Wproj^T + bproj
    gemm_bt<<<dim3(2, 32, Bb_), 256, 0, stream>>>(
        refsT, Wprojb, nullptr, catT, Nn_, C, C, C, C, 2 * C,
        MN, 0, (long)Nn_ * 2 * C,
        nullptr, bproj, 0, nullptr, qryTb, C, MN, 1.0f, 0);

    // 7. catT[:, 256:] = fused cross attention (+qryTb, +bout)
    cross_fused<<<Bb_ * (Nn_ / 64), 256, 0, stream>>>(
        x2T, qryTb, ktil, betab, vtil, bout, catT);

    // 8. implicit conv3x3 (tap-split, bf16 partials) + reduce(relu) -> y1T
    conv3x3_gemm<<<dim3(2, 32, Bb_ * 3), 256, 0, stream>>>(catT, Wtap, convPart);
    for (int b = 0; b < Bb_; ++b)
        reduce_partials<<<(int)(MN / 1024), 256, 0, stream>>>(
            convPart + (long)b * 3 * MN, MN, y1T + (long)b * MN, MN);

    // 9. out = qry + Wf2 @ y1 + bf2   (fp32 [B][C][N])
    gemm_bt<<<dim3(32, 2, Bb_), 256, 0, stream>>>(
        Wf2b, y1T, out, nullptr, C, Nn_, C, C, C, Nn_,
        0, MN, CN,
        bf2, nullptr, 0, qry, nullptr, Nn_, CN, 1.0f, 0);
}

// Round 14
// 260.663 us; speedup vs baseline: 1.1177x; 1.1177x over previous
//
#include <hip/hip_runtime.h>
#include <hip/hip_bf16.h>

#define C 256
#define HID 128
#define Bb_ 2
#define Hh 64
#define Ww 64
#define Nn_ 4096
#define NP 16
#define NC 16
#define KVSPLIT 8
#define KVB 32

typedef __bf16 bf16x8 __attribute__((ext_vector_type(8)));
typedef float f32x4 __attribute__((ext_vector_type(4)));

// ---------------------------------------------------------------------------
// Coalesced tiled LayerNorm -> x1T, x2T bf16 [B][N][C]; also emits qryT bf16.
__global__ __launch_bounds__(256) void lnT_kernel(
    const float* __restrict__ x,
    const float* __restrict__ g1, const float* __restrict__ b1,
    const float* __restrict__ g2, const float* __restrict__ b2,
    __hip_bfloat16* __restrict__ x1T, __hip_bfloat16* __restrict__ x2T,
    __hip_bfloat16* __restrict__ qryTb)
{
    int blk = blockIdx.x;
    int b = blk >> 6;
    int n0 = (blk & 63) << 6;
    int t = threadIdx.x;
    __shared__ __hip_bfloat16 xs[64][258];
    __shared__ float rs4[4][64], rq4[4][64], mean[64], inv[64];
    int j = t & 63, cg = t >> 6;
    float s = 0.f, q = 0.f;
    for (int it = 0; it < 64; ++it) {
        int c = it * 4 + cg;
        float v = x[((long)b * C + c) * Nn_ + n0 + j];
        xs[j][c] = __float2bfloat16(v);
        s += v; q += v * v;
    }
    rs4[cg][j] = s; rq4[cg][j] = q;
    __syncthreads();
    if (t < 64) {
        float S = rs4[0][t] + rs4[1][t] + rs4[2][t] + rs4[3][t];
        float Q = rq4[0][t] + rq4[1][t] + rq4[2][t] + rq4[3][t];
        float m = S * (1.0f / C);
        float var = Q * (1.0f / C) - m * m;
        mean[t] = m; inv[t] = rsqrtf(var + 1e-5f);
    }
    __syncthreads();
    float G1 = g1[t], B1 = b1[t], G2 = g2[t], B2 = b2[t];
    for (int j2 = 0; j2 < 64; ++j2) {
        float v = __bfloat162float(xs[j2][t]);
        float xn = (v - mean[j2]) * inv[j2];
        long o = ((long)b * Nn_ + n0 + j2) * C + t;
        x1T[o] = __float2bfloat16(xn * G1 + B1);
        x2T[o] = __float2bfloat16(xn * G2 + B2);
        qryTb[o] = xs[j2][t];
    }
}

// ---------------------------------------------------------------------------
__global__ __launch_bounds__(256) void gate_kernel(
    const float* __restrict__ arch, const float* __restrict__ Wg,
    const float* __restrict__ bg, float* __restrict__ gate)
{
    int b = blockIdx.x;
    int o = threadIdx.x;
    __shared__ float guide[C];
    float s = 0.f;
    for (int p = 0; p < NP; ++p) s += arch[(long)b * NP * C + (long)p * C + o];
    guide[o] = s * (1.0f / NP);
    __syncthreads();
    float acc = bg[o];
    for (int cc = 0; cc < C; ++cc) acc += guide[cc] * Wg[(long)o * C + cc];
    gate[b * C + o] = 1.0f / (1.0f + __expf(-acc));
}

// ---------------------------------------------------------------------------
#define QSCALE 0.09016844005429271f   // log2(e)/16
__global__ __launch_bounds__(256) void build_wqkv(
    const float* __restrict__ Wqkv, const float* __restrict__ bqkv,
    const float* __restrict__ gate,
    __hip_bfloat16* __restrict__ WqkvG, float* __restrict__ biasCol)
{
    long i = (long)blockIdx.x * 256 + threadIdx.x;
    long total = (long)Bb_ * 3 * C * C;
    if (i < total) {
        long b = i / (3 * C * C);
        long rem = i % (3 * C * C);
        int o = (int)(rem / C);
        float v = Wqkv[rem];
        if (o < C) v *= QSCALE;
        else if (o < 2 * C) v *= gate[b * C + (o - C)];
        WqkvG[i] = __float2bfloat16(v);
    }
    if (i < (long)Bb_ * 3 * C) {
        long b = i / (3 * C);
        int o = (int)(i % (3 * C));
        float v = bqkv[o];
        if (o < C) v *= QSCALE;
        else if (o < 2 * C) v *= gate[b * C + (o - C)];
        biasCol[i] = v;
    }
}

// ---------------------------------------------------------------------------
// Cast Wproj, Wf2 to bf16 and build Wtap [9][O][512] from Wf1.
__global__ __launch_bounds__(256) void cast_all(
    const float* __restrict__ Wproj, const float* __restrict__ Wf2,
    const float* __restrict__ Wf1,
    __hip_bfloat16* __restrict__ Wprojb, __hip_bfloat16* __restrict__ Wf2b,
    __hip_bfloat16* __restrict__ Wtap)
{
    long i = (long)blockIdx.x * 256 + threadIdx.x;
    const long nP = (long)C * C;
    const long nT = 9l * C * 2 * C;
    if (i < nP) { Wprojb[i] = __float2bfloat16(Wproj[i]); return; }
    i -= nP;
    if (i < nP) { Wf2b[i] = __float2bfloat16(Wf2[i]); return; }
    i -= nP;
    if (i < nT) {
        int tap = (int)(i / (C * 2 * C));
        long rem = i % (C * 2 * C);
        int o = (int)(rem / (2 * C)), ic = (int)(rem % (2 * C));
        Wtap[i] = __float2bfloat16(Wf1[((long)o * 2 * C + ic) * 9 + tap]);
    }
}

// ---------------------------------------------------------------------------
// Cross-attention algebraic prep (fold Wq/Wout through the 16-token attn).
__global__ __launch_bounds__(256) void cross_prep(
    const float* __restrict__ ctx, const float* __restrict__ Wkv,
    const float* __restrict__ bkv, const float* __restrict__ Wq,
    const float* __restrict__ bq, const float* __restrict__ Wout,
    float* __restrict__ ktil, float* __restrict__ beta,
    float* __restrict__ vtil)
{
    int b = blockIdx.x >> 4, m = blockIdx.x & 15;
    int t = threadIdx.x;
    __shared__ float cs[C], kl[C], red[128];
    cs[t] = ctx[((long)b * NC + m) * C + t];
    __syncthreads();
    float acc = bkv[t];
    for (int c = 0; c < C; ++c) acc += cs[c] * Wkv[(long)t * C + c];
    kl[t] = acc;
    __syncthreads();
    const float scc = 0.08838834764831845f;
    float kt = 0.f;
    for (int h = 0; h < HID; ++h) kt += kl[h] * Wq[(long)h * C + t];
    ktil[((long)b * NC + m) * C + t] = kt * scc;
    float vt = 0.f;
    for (int h = 0; h < HID; ++h) vt += kl[HID + h] * Wout[(long)t * HID + h];
    vtil[((long)b * C + t) * NC + m] = vt;
    if (t < 128) red[t] = bq[t] * kl[t];
    __syncthreads();
    for (int s = 64; s > 0; s >>= 1) {
        if (t < s) red[t] += red[t + s];
        __syncthreads();
    }
    if (t == 0) beta[b * NC + m] = red[0] * scc;
}

// ---------------------------------------------------------------------------
// Fused cross attention -> catT right half (qryT bf16)
__global__ __launch_bounds__(256) void cross_fused(
    const __hip_bfloat16* __restrict__ x2T, const __hip_bfloat16* __restrict__ qryTb,
    const float* __restrict__ ktil, const float* __restrict__ beta,
    const float* __restrict__ vtil, const float* __restrict__ bout,
    __hip_bfloat16* __restrict__ catT)
{
    int blk = blockIdx.x;
    int b = blk >> 6;
    long n = (long)(blk & 63) * 64 + (threadIdx.x >> 2);
    int cg = threadIdx.x & 3;
    int t = threadIdx.x;
    __shared__ float kt[NC * C];
    __shared__ float vt[C * NC];
    for (int r = 0; r < 16; ++r) {
        int idx = r * 256 + t;
        int m = idx >> 8, c = idx & 255;
        kt[m * 256 + (c & 63) * 4 + (c >> 6)] = ktil[((long)b * NC + m) * C + c];
        int c2 = idx >> 4, m2 = idx & 15;
        vt[((c2 & 63) * 4 + (c2 >> 6)) * 16 + m2] = vtil[((long)b * C + c2) * NC + m2];
    }
    __syncthreads();

    float s[NC];
    #pragma unroll
    for (int m = 0; m < NC; ++m) s[m] = 0.f;
    const __hip_bfloat16* xr = x2T + ((long)b * Nn_ + n) * C + cg * 64;
    for (int c8 = 0; c8 < 8; ++c8) {
        bf16x8 xv = *(const bf16x8*)(xr + c8 * 8);
        #pragma unroll
        for (int e = 0; e < 8; ++e) {
            float xf = (float)xv[e];
            int ic = c8 * 8 + e;
            #pragma unroll
            for (int m = 0; m < NC; ++m)
                s[m] += xf * kt[m * 256 + ic * 4 + cg];
        }
    }
    #pragma unroll
    for (int m = 0; m < NC; ++m) {
        s[m] += __shfl_xor(s[m], 1);
        s[m] += __shfl_xor(s[m], 2);
        s[m] += beta[b * NC + m];
    }
    float mx = -1e30f;
    #pragma unroll
    for (int m = 0; m < NC; ++m) mx = fmaxf(mx, s[m]);
    float sum = 0.f;
    #pragma unroll
    for (int m = 0; m < NC; ++m) { s[m] = __expf(s[m] - mx); sum += s[m]; }
    float dn = 1.0f / sum;

    const __hip_bfloat16* qr = qryTb + ((long)b * Nn_ + n) * C + cg * 64;
    __hip_bfloat16* outp = catT + ((long)b * Nn_ + n) * (2 * C) + C + cg * 64;
    for (int c8 = 0; c8 < 8; ++c8) {
        union { ushort4 u; __hip_bfloat16 h[4]; } cv0, cv1;
        #pragma unroll
        for (int e = 0; e < 8; ++e) {
            int ic = c8 * 8 + e;
            int c = cg * 64 + ic;
            float acc = __bfloat162float(qr[ic]) + bout[c];
            float pv = 0.f;
            #pragma unroll
            for (int m = 0; m < NC; ++m)
                pv += vt[(ic * 4 + cg) * 16 + m] * s[m];
            acc += pv * dn;
            if (e < 4) cv0.h[e] = __float2bfloat16(acc);
            else       cv1.h[e - 4] = __float2bfloat16(acc);
        }
        *(ushort4*)(outp + c8 * 8) = cv0.u;
        *(ushort4*)(outp + c8 * 8 + 4) = cv1.u;
    }
}

// ---------------------------------------------------------------------------
// MFMA bf16 GEMM; resid may be fp32 or bf16.
__global__ __launch_bounds__(256) void gemm_bt(
    const __hip_bfloat16* __restrict__ A,
    const __hip_bfloat16* __restrict__ Bt,
    float* __restrict__ D,
    __hip_bfloat16* __restrict__ Dbf,
    int M, int N, int K, int lda, int ldb, int ldd,
    long batchA, long batchB, long batchD,
    const float* __restrict__ biasRow,
    const float* __restrict__ biasCol, long bcStride,
    const float* __restrict__ resid,
    const __hip_bfloat16* __restrict__ residB, int ldr, long batchR,
    float alpha, int relu)
{
    __shared__ __align__(16) __hip_bfloat16 As[128 * 32];
    __shared__ __align__(16) __hip_bfloat16 Bs[128 * 32];
    int bz = blockIdx.z;
    const __hip_bfloat16* Ab = A + (long)bz * batchA;
    const __hip_bfloat16* Bb = Bt + (long)bz * batchB;
    int m0 = blockIdx.y * 128, n0 = blockIdx.x * 128;
    int tid = threadIdx.x;
    int lane = tid & 63, wave = tid >> 6;
    int wr = wave >> 1, wc = wave & 1;
    int lr = lane & 15, lg = lane >> 4;

    f32x4 acc[4][4];
    #pragma unroll
    for (int i = 0; i < 4; ++i)
        #pragma unroll
        for (int j = 0; j < 4; ++j)
            #pragma unroll
            for (int r = 0; r < 4; ++r) acc[i][j][r] = 0.f;

    for (int k0 = 0; k0 < K; k0 += 32) {
        #pragma unroll
        for (int q = 0; q < 2; ++q) {
            int idx = q * 256 + tid;
            int row = idx >> 2;
            int ke = (idx & 3) * 8;
            uint4 va = *(const uint4*)(Ab + (long)(m0 + row) * lda + k0 + ke);
            uint4 vb = *(const uint4*)(Bb + (long)(n0 + row) * ldb + k0 + ke);
            ((uint4*)As)[idx] = va;
            ((uint4*)Bs)[idx] = vb;
        }
        __syncthreads();
        bf16x8 af[4], bfr[4];
        #pragma unroll
        for (int i = 0; i < 4; ++i)
            af[i] = *(const bf16x8*)(As + (wr * 64 + i * 16 + lr) * 32 + lg * 8);
        #pragma unroll
        for (int j = 0; j < 4; ++j)
            bfr[j] = *(const bf16x8*)(Bs + (wc * 64 + j * 16 + lr) * 32 + lg * 8);
        #pragma unroll
        for (int i = 0; i < 4; ++i)
            #pragma unroll
            for (int j = 0; j < 4; ++j)
                acc[i][j] = __builtin_amdgcn_mfma_f32_16x16x32_bf16(af[i], bfr[j], acc[i][j], 0, 0, 0);
        __syncthreads();
    }

    int colc = n0 + wc * 64 + lr;
    #pragma unroll
    for (int i = 0; i < 4; ++i) {
        #pragma unroll
        for (int r = 0; r < 4; ++r) {
            int row = m0 + wr * 64 + i * 16 + lg * 4 + r;
            float brv = biasRow ? biasRow[row] : 0.f;
            #pragma unroll
            for (int j = 0; j < 4; ++j) {
                int cc = colc + j * 16;
                float v = acc[i][j][r] * alpha + brv;
                if (biasCol) v += biasCol[bz * bcStride + cc];
                if (resid) v += resid[(long)bz * batchR + (long)row * ldr + cc];
                if (residB) v += __bfloat162float(residB[(long)bz * batchR + (long)row * ldr + cc]);
                if (relu) v = fmaxf(v, 0.f);
                long oa = (long)bz * batchD + (long)row * ldd + cc;
                if (Dbf) Dbf[oa] = __float2bfloat16(v);
                else     D[oa] = v;
            }
        }
    }
}

// ---------------------------------------------------------------------------
__global__ __launch_bounds__(256) void extract_v(
    const __hip_bfloat16* __restrict__ qkvT, __hip_bfloat16* __restrict__ vB)
{
    int b = blockIdx.z;
    int c0 = blockIdx.y * 64, m0 = blockIdx.x * 64;
    __shared__ __hip_bfloat16 tb[64][66];
    int tx = threadIdx.x & 63, tg = threadIdx.x >> 6;
    for (int rr = tg; rr < 64; rr += 4)
        tb[rr][tx] = qkvT[((long)b * Nn_ + m0 + rr) * (3 * C) + 2 * C + c0 + tx];
    __syncthreads();
    for (int rr = tg; rr < 64; rr += 4)
        vB[((long)b * C + c0 + rr) * Nn_ + m0 + tx] = tb[tx][rr];
}

// ---------------------------------------------------------------------------
// Flash attention (round-12 version: best measured at 70us).
// KVB=32 -> 36KB LDS -> 4 blocks/CU. XOR-swizzled LDS; bf16 Opart.
__global__ __launch_bounds__(256) void flash_attn(
    const __hip_bfloat16* __restrict__ qkvT,
    const __hip_bfloat16* __restrict__ vB,
    __hip_bfloat16* __restrict__ Opart,   // [B][KVSPLIT][N][256] bf16
    float* __restrict__ lsum)             // [B][KVSPLIT][N]
{
    int qb = blockIdx.x, sp = blockIdx.y, b = blockIdx.z;
    int n0 = qb * 64;
    int tid = threadIdx.x;
    int lane = tid & 63, w = tid >> 6;
    int lr = lane & 15, lg = lane >> 4;

    __shared__ __align__(16) char Ks[32 * 512];
    __shared__ __align__(16) char Vs[128 * 128];
    __shared__ __align__(16) char Pl[32 * 128];

    bf16x8 qf[8];
    {
        const __hip_bfloat16* qp = qkvT + ((long)b * Nn_ + n0 + w * 16 + lr) * (3 * C);
        #pragma unroll
        for (int ks = 0; ks < 8; ++ks)
            qf[ks] = *(const bf16x8*)(qp + ks * 32 + lg * 8);
    }

    const __hip_bfloat16* kbase = qkvT + ((long)b * Nn_) * (3 * C) + C;
    const __hip_bfloat16* vbase = vB + (long)b * C * Nn_;
    int kvBeg = sp * (Nn_ / KVSPLIT);

    int krow[4], kc[4], koff[4], vd[4], vc[4], voff[4];
    #pragma unroll
    for (int ps = 0; ps < 4; ++ps) {
        int id = ps * 256 + tid;
        krow[ps] = id >> 5; kc[ps] = id & 31;
        koff[ps] = krow[ps] * 512 + ((kc[ps] * 16) ^ ((krow[ps] & 7) << 4));
        vd[ps] = id >> 2; vc[ps] = id & 3;
        int vp = vd[ps] >> 1;
        voff[ps] = vp * 128 + ((((vd[ps] & 1) * 64) + vc[ps] * 16) ^ ((vp & 7) << 4));
    }

    f32x4 Oacc[16];
    #pragma unroll
    for (int jd = 0; jd < 16; ++jd)
        #pragma unroll
        for (int r = 0; r < 4; ++r) Oacc[jd][r] = 0.f;
    float l_r[4] = {0.f, 0.f, 0.f, 0.f};

    const int NT = (Nn_ / KVSPLIT) / KVB;   // 16
    for (int t = 0; t < NT; ++t) {
        int kv0 = kvBeg + t * KVB;
        uint4 kr[4], vr[4];
        #pragma unroll
        for (int ps = 0; ps < 4; ++ps) {
            kr[ps] = *(const uint4*)(kbase + (long)(kv0 + krow[ps]) * (3 * C) + kc[ps] * 8);
            vr[ps] = *(const uint4*)(vbase + (long)vd[ps] * Nn_ + kv0 + vc[ps] * 8);
        }
        #pragma unroll
        for (int ps = 0; ps < 4; ++ps) {
            *(uint4*)(Ks + koff[ps]) = kr[ps];
            *(uint4*)(Vs + voff[ps]) = vr[ps];
        }
        __syncthreads();
        // ---- S = Q K^T (log2-domain)
        f32x4 sacc[2];
        #pragma unroll
        for (int j = 0; j < 2; ++j)
            #pragma unroll
            for (int r = 0; r < 4; ++r) sacc[j][r] = 0.f;
        __builtin_amdgcn_s_setprio(1);
        #pragma unroll
        for (int ks = 0; ks < 8; ++ks) {
            #pragma unroll
            for (int j = 0; j < 2; ++j) {
                int row = j * 16 + lr;
                bf16x8 kf = *(const bf16x8*)(Ks + row * 512 +
                            ((ks * 64 + lg * 16) ^ ((row & 7) << 4)));
                sacc[j] = __builtin_amdgcn_mfma_f32_16x16x32_bf16(qf[ks], kf, sacc[j], 0, 0, 0);
            }
        }
        __builtin_amdgcn_s_setprio(0);
        // ---- P = exp2(S) -> Pl
        #pragma unroll
        for (int j = 0; j < 2; ++j)
            #pragma unroll
            for (int r = 0; r < 4; ++r) {
                float p = __builtin_amdgcn_exp2f(sacc[j][r]);
                l_r[r] += p;
                int prow = w * 16 + 4 * lg + r;
                int pp = prow >> 1;
                *(__hip_bfloat16*)(Pl + pp * 128 +
                    ((((prow & 1) * 64) + (j * 16 + lr) * 2) ^ ((pp & 7) << 4))) =
                    __float2bfloat16(p);
            }
        // ---- O += P V^T
        __builtin_amdgcn_s_setprio(1);
        {
            int prow = w * 16 + lr;
            int pp = prow >> 1;
            bf16x8 pf = *(const bf16x8*)(Pl + pp * 128 +
                        ((((prow & 1) * 64) + lg * 16) ^ ((pp & 7) << 4)));
            #pragma unroll
            for (int jd = 0; jd < 16; ++jd) {
                int vrw = jd * 16 + lr;
                int vp = vrw >> 1;
                bf16x8 vf = *(const bf16x8*)(Vs + vp * 128 +
                            ((((vrw & 1) * 64) + lg * 16) ^ ((vp & 7) << 4)));
                Oacc[jd] = __builtin_amdgcn_mfma_f32_16x16x32_bf16(pf, vf, Oacc[jd], 0, 0, 0);
            }
        }
        __builtin_amdgcn_s_setprio(0);
        __syncthreads();
    }

    #pragma unroll
    for (int r = 0; r < 4; ++r) {
        float v = l_r[r];
        #pragma unroll
        for (int off = 1; off <= 8; off <<= 1)
            v += __shfl_xor(v, off);
        l_r[r] = v;
    }

    __hip_bfloat16* Op = Opart + (((long)b * KVSPLIT + sp) * Nn_ + n0) * 256;
    #pragma unroll
    for (int jd = 0; jd < 16; ++jd)
        #pragma unroll
        for (int r = 0; r < 4; ++r) {
            int row = w * 16 + lg * 4 + r;
            Op[(long)row * 256 + jd * 16 + lr] = __float2bfloat16(Oacc[jd][r]);
        }
    if (lr == 0) {
        float* lp = lsum + ((long)b * KVSPLIT + sp) * Nn_ + n0;
        #pragma unroll
        for (int r = 0; r < 4; ++r)
            lp[w * 16 + lg * 4 + r] = l_r[r];
    }
}

// ---------------------------------------------------------------------------
__global__ __launch_bounds__(256) void merge_flash(
    const __hip_bfloat16* __restrict__ Opart, const float* __restrict__ lsum,
    __hip_bfloat16* __restrict__ refsT)
{
    long gi = (long)blockIdx.x * 256 + threadIdx.x;
    long row = gi >> 6;
    int c4 = (int)(gi & 63) * 4;
    long b = row / Nn_, n = row % Nn_;
    float l = 0.f;
    float o0 = 0.f, o1 = 0.f, o2 = 0.f, o3 = 0.f;
    #pragma unroll
    for (int sp = 0; sp < KVSPLIT; ++sp) {
        long rr = (b * KVSPLIT + sp) * Nn_ + n;
        l += lsum[rr];
        union { ushort4 u; __hip_bfloat16 h[4]; } rv;
        rv.u = *(const ushort4*)(Opart + rr * 256 + c4);
        o0 += __bfloat162float(rv.h[0]);
        o1 += __bfloat162float(rv.h[1]);
        o2 += __bfloat162float(rv.h[2]);
        o3 += __bfloat162float(rv.h[3]);
    }
    float dn = 1.0f / l;
    union { ushort4 u; __hip_bfloat16 h[4]; } cv;
    cv.h[0] = __float2bfloat16(o0 * dn);
    cv.h[1] = __float2bfloat16(o1 * dn);
    cv.h[2] = __float2bfloat16(o2 * dn);
    cv.h[3] = __float2bfloat16(o3 * dn);
    *(ushort4*)(refsT + (b * Nn_ + n) * 256 + c4) = cv.u;
}

// ---------------------------------------------------------------------------
// Implicit-GEMM 3x3 conv, FULL 9-way tap-split for occupancy (1152 blocks).
// partials bf16 [B][9][N][256]; K = 512 per block.
__global__ __launch_bounds__(256) void conv3x3_gemm(
    const __hip_bfloat16* __restrict__ catT,
    const __hip_bfloat16* __restrict__ Wtap,
    __hip_bfloat16* __restrict__ partials)
{
    __shared__ __align__(16) __hip_bfloat16 As[128 * 32];
    __shared__ __align__(16) __hip_bfloat16 Bs[128 * 32];
    int z = blockIdx.z;
    int b = z / 9, sp = z % 9;
    int dh = sp / 3 - 1, dw = sp % 3 - 1;
    int o0 = blockIdx.x * 128, m0 = blockIdx.y * 128;
    int tid = threadIdx.x;
    int lane = tid & 63, wave = tid >> 6;
    int wr = wave >> 1, wc = wave & 1;
    int lr = lane & 15, lg = lane >> 4;
    const __hip_bfloat16* cb = catT + (long)b * Nn_ * (2 * C);
    const __hip_bfloat16* wt = Wtap + (long)sp * C * (2 * C);

    f32x4 acc[4][4];
    #pragma unroll
    for (int i = 0; i < 4; ++i)
        #pragma unroll
        for (int j = 0; j < 4; ++j)
            #pragma unroll
            for (int r = 0; r < 4; ++r) acc[i][j][r] = 0.f;

    for (int k0 = 0; k0 < 2 * C; k0 += 32) {
        #pragma unroll
        for (int q = 0; q < 2; ++q) {
            int idx = q * 256 + tid;
            int row = idx >> 2;
            int ke = (idx & 3) * 8;
            int gm = m0 + row;
            int h = (gm >> 6) + dh, w2 = (gm & 63) + dw;
            uint4 va = {0, 0, 0, 0};
            if ((unsigned)h < 64u && (unsigned)w2 < 64u)
                va = *(const uint4*)(cb + ((long)((h << 6) + w2)) * (2 * C) + k0 + ke);
            ((uint4*)As)[idx] = va;
            ((uint4*)Bs)[idx] = *(const uint4*)(wt + (long)(o0 + row) * (2 * C) + k0 + ke);
        }
        __syncthreads();
        bf16x8 af[4], bfr[4];
        #pragma unroll
        for (int i = 0; i < 4; ++i)
            af[i] = *(const bf16x8*)(As + (wr * 64 + i * 16 + lr) * 32 + lg * 8);
        #pragma unroll
        for (int j = 0; j < 4; ++j)
            bfr[j] = *(const bf16x8*)(Bs + (wc * 64 + j * 16 + lr) * 32 + lg * 8);
        #pragma unroll
        for (int i = 0; i < 4; ++i)
            #pragma unroll
            for (int j = 0; j < 4; ++j)
                acc[i][j] = __builtin_amdgcn_mfma_f32_16x16x32_bf16(af[i], bfr[j], acc[i][j], 0, 0, 0);
        __syncthreads();
    }

    __hip_bfloat16* Dp = partials + ((long)(b * 9 + sp) * Nn_ + m0) * 256;
    #pragma unroll
    for (int i = 0; i < 4; ++i)
        #pragma unroll
        for (int r = 0; r < 4; ++r) {
            int row = wr * 64 + i * 16 + lg * 4 + r;
            #pragma unroll
            for (int j = 0; j < 4; ++j)
                Dp[(long)row * 256 + o0 + wc * 64 + j * 16 + lr] =
                    __float2bfloat16(acc[i][j][r]);
        }
}

// ---------------------------------------------------------------------------
// Sum 9 bf16 tap-partials -> y1T bf16 with relu.
__global__ __launch_bounds__(256) void reduce_partials(
    const __hip_bfloat16* __restrict__ part, long partStride,
    __hip_bfloat16* __restrict__ out, long n)
{
    long i = ((long)blockIdx.x * 256 + threadIdx.x) * 4;
    if (i >= n) return;
    float a[4] = {0.f, 0.f, 0.f, 0.f};
    #pragma unroll
    for (int sp = 0; sp < 9; ++sp) {
        union { ushort4 u; __hip_bfloat16 h[4]; } rv;
        rv.u = *(const ushort4*)(part + (long)sp * partStride + i);
        #pragma unroll
        for (int k = 0; k < 4; ++k) a[k] += __bfloat162float(rv.h[k]);
    }
    union { ushort4 u; __hip_bfloat16 h[4]; } cv;
    #pragma unroll
    for (int k = 0; k < 4; ++k)
        cv.h[k] = __float2bfloat16(fmaxf(a[k], 0.f));
    *(ushort4*)(out + i) = cv.u;
}

// ---------------------------------------------------------------------------
extern "C" void kernel_launch(void* const* d_in, const int* in_sizes, int n_in,
                              void* d_out, int out_size, void* d_ws, size_t ws_size,
                              hipStream_t stream)
{
    const float* qry   = (const float*)d_in[0];
    const float* arch  = (const float*)d_in[1];
    const float* ctx   = (const float*)d_in[2];
    const float* ln1_g = (const float*)d_in[3];
    const float* ln1_b = (const float*)d_in[4];
    const float* Wqkv  = (const float*)d_in[5];
    const float* bqkv  = (const float*)d_in[6];
    const float* Wproj = (const float*)d_in[7];
    const float* bproj = (const float*)d_in[8];
    const float* Wg    = (const float*)d_in[9];
    const float* bg    = (const float*)d_in[10];
    const float* ln2_g = (const float*)d_in[11];
    const float* ln2_b = (const float*)d_in[12];
    const float* Wq    = (const float*)d_in[13];
    const float* bq    = (const float*)d_in[14];
    const float* Wkv   = (const float*)d_in[15];
    const float* bkv   = (const float*)d_in[16];
    const float* Wout  = (const float*)d_in[17];
    const float* bout  = (const float*)d_in[18];
    const float* Wf1   = (const float*)d_in[19];
    const float* Wf2   = (const float*)d_in[20];
    const float* bf2   = (const float*)d_in[21];
    float* out = (float*)d_out;

    const long CN = (long)C * Nn_;
    const long MN = (long)Nn_ * C;
    char* ws = (char*)d_ws;
    size_t off = 0;
    auto alloc = [&](size_t bytes) -> char* {
        char* p = ws + off;
        off += (bytes + 255) & ~size_t(255);
        return p;
    };
    float* lbuf     = (float*)alloc((long)Bb_ * KVSPLIT * Nn_ * 4);
    float* gate     = (float*)alloc(Bb_ * C * 4);
    float* biasCol  = (float*)alloc((long)Bb_ * 3 * C * 4);
    float* ktil     = (float*)alloc((long)Bb_ * NC * C * 4);
    float* betab    = (float*)alloc((long)Bb_ * NC * 4);
    float* vtil     = (float*)alloc((long)Bb_ * C * NC * 4);
    __hip_bfloat16* Opart = (__hip_bfloat16*)alloc((long)Bb_ * KVSPLIT * MN * 2);  // 32MB
    __hip_bfloat16* convPart = (__hip_bfloat16*)alloc((long)Bb_ * 9 * MN * 2);     // 37.7MB
    __hip_bfloat16* qryTb = (__hip_bfloat16*)alloc(Bb_ * MN * 2);
    __hip_bfloat16* x1T   = (__hip_bfloat16*)alloc(Bb_ * MN * 2);
    __hip_bfloat16* x2T   = (__hip_bfloat16*)alloc(Bb_ * MN * 2);
    __hip_bfloat16* qkvT  = (__hip_bfloat16*)alloc((long)Bb_ * Nn_ * 3 * C * 2);
    __hip_bfloat16* vB    = (__hip_bfloat16*)alloc(Bb_ * CN * 2);
    __hip_bfloat16* refsT = (__hip_bfloat16*)alloc(Bb_ * MN * 2);
    __hip_bfloat16* catT  = (__hip_bfloat16*)alloc((long)Bb_ * Nn_ * 2 * C * 2);
    __hip_bfloat16* y1T   = (__hip_bfloat16*)alloc(Bb_ * MN * 2);
    __hip_bfloat16* WqkvG = (__hip_bfloat16*)alloc((long)Bb_ * 3 * C * C * 2);
    __hip_bfloat16* Wprojb= (__hip_bfloat16*)alloc((long)C * C * 2);
    __hip_bfloat16* Wf2b  = (__hip_bfloat16*)alloc((long)C * C * 2);
    __hip_bfloat16* Wtap  = (__hip_bfloat16*)alloc((long)9 * C * 2 * C * 2);

    // 1. layernorm (+ bf16 qry transpose fused)
    lnT_kernel<<<Bb_ * (Nn_ / 64), 256, 0, stream>>>(
        qry, ln1_g, ln1_b, ln2_g, ln2_b, x1T, x2T, qryTb);

    // 2. gate + weight prep + cross prep
    gate_kernel<<<Bb_, 256, 0, stream>>>(arch, Wg, bg, gate);
    build_wqkv<<<(Bb_ * 3 * C * C + 255) / 256, 256, 0, stream>>>(Wqkv, bqkv, gate, WqkvG, biasCol);
    {
        long total = (long)C * C * 2 + 9l * C * 2 * C;
        cast_all<<<(int)((total + 255) / 256), 256, 0, stream>>>(
            Wproj, Wf2, Wf1, Wprojb, Wf2b, Wtap);
    }
    cross_prep<<<Bb_ * NC, 256, 0, stream>>>(ctx, Wkv, bkv, Wq, bq, Wout, ktil, betab, vtil);

    // 3. qkvT = x1T @ WqkvG^T + biasCol  -> bf16 [B][N][768]
    gemm_bt<<<dim3(6, 32, Bb_), 256, 0, stream>>>(
        x1T, WqkvG, nullptr, qkvT, Nn_, 3 * C, C, C, C, 3 * C,
        MN, (long)3 * C * C, (long)Nn_ * 3 * C,
        nullptr, biasCol, 3 * C, nullptr, nullptr, 0, 0, 1.0f, 0);

    // 4. v -> vB [B][C][N]
    extract_v<<<dim3(Nn_ / 64, C / 64, Bb_), 256, 0, stream>>>(qkvT, vB);

    // 5. flash attention + merge -> refsT bf16 [B][N][C]
    flash_attn<<<dim3(Nn_ / 64, KVSPLIT, Bb_), 256, 0, stream>>>(qkvT, vB, Opart, lbuf);
    merge_flash<<<(int)((long)Bb_ * Nn_ * 64 / 256), 256, 0, stream>>>(Opart, lbuf, refsT);

    // 6. catT[:, :256] = qryTb + refsT @ Wproj^T + bproj
    gemm_bt<<<dim3(2, 32, Bb_), 256, 0, stream>>>(
        refsT, Wprojb, nullptr, catT, Nn_, C, C, C, C, 2 * C,
        MN, 0, (long)Nn_ * 2 * C,
        nullptr, bproj, 0, nullptr, qryTb, C, MN, 1.0f, 0);

    // 7. catT[:, 256:] = fused cross attention (+qryTb, +bout)
    cross_fused<<<Bb_ * (Nn_ / 64), 256, 0, stream>>>(
        x2T, qryTb, ktil, betab, vtil, bout, catT);

    // 8. implicit conv3x3 (9-way tap-split, bf16 partials) + reduce(relu)
    conv3x3_gemm<<<dim3(2, 32, Bb_ * 9), 256, 0, stream>>>(catT, Wtap, convPart);
    for (int b = 0; b < Bb_; ++b)
        reduce_partials<<<(int)(MN / 1024), 256, 0, stream>>>(
            convPart + (long)b * 9 * MN, MN, y1T + (long)b * MN, MN);

    // 9. out = qry + Wf2 @ y1 + bf2   (fp32 [B][C][N])
    gemm_bt<<<dim3(32, 2, Bb_), 256, 0, stream>>>(
        Wf2b, y1T, out, nullptr, C, Nn_, C, C, C, Nn_,
        0, MN, CN,
        bf2, nullptr, 0, qry, nullptr, Nn_, CN, 1.0f, 0);
}